// Round 5
// baseline (94.301 us; speedup 1.0000x reference)
//
#include <hip/hip_runtime.h>
#include <math.h>

// Layout: sample = 16 lanes x 16 slots; 2 samples/thread. SoA slot-pair packing:
//   pack k (k=0..7) holds slots (2k, 2k+1); Re[k]=(re[2k],re[2k+1]), Im[k] likewise.
// Qubit q in 0..3 -> lane bit (3-q) of (tid&15)
// Qubit 4 -> pack bit2, qubit 5 -> pack bit1, qubit 6 -> pack bit0, qubit 7 -> intra-pack half.
// Gate constants pre-splatted in LDS; complex MACs = packed FMA chains, no swaps.
// Circuit: init(RX+Rot0 folded) -> ring1 -> Rot1 -> ring2 -> Rot2 -> ring3 -> Rot3 -> readout(ring4 folded).

typedef float v2f __attribute__((ext_vector_type(2)));

// ---- cross-lane xor within 16-lane rows (verified primitives) ----
template<int CTRL>
__device__ __forceinline__ float dppf(float v) {
    const int i = __float_as_int(v);
    return __int_as_float(__builtin_amdgcn_update_dpp(i, i, CTRL, 0xF, 0xF, true));
}
template<int M>
__device__ __forceinline__ float lxorf(float v) {
    static_assert(M == 1 || M == 2 || M == 4 || M == 8, "bad mask");
    if constexpr (M == 1)      return dppf<0xB1>(v);   // quad_perm [1,0,3,2]
    else if constexpr (M == 2) return dppf<0x4E>(v);   // quad_perm [2,3,0,1]
    else if constexpr (M == 4) return __int_as_float(__builtin_amdgcn_ds_swizzle(__float_as_int(v), 0x101F));
    else                       return __int_as_float(__builtin_amdgcn_ds_swizzle(__float_as_int(v), 0x201F));
}
template<int M>
__device__ __forceinline__ v2f lxor2(v2f v) {
    v2f r; r.x = lxorf<M>(v.x); r.y = lxorf<M>(v.y); return r;
}
__device__ __forceinline__ v2f sw2(v2f v) { return __builtin_shufflevector(v, v, 1, 0); }

struct St { v2f re[8]; v2f im[8]; };

// ---------------- Rot gates ----------------
// lane gate on qubit Q (LM = 1<<(3-Q)); coefficients preselected by side:
//   cA = diag coeff (on my amp), cB = offdiag (on partner amp), each splatted (r,i).
template<int LM>
__device__ __forceinline__ void rot_lane(St& A, St& B, v2f cAr, v2f cAi, v2f cBr, v2f cBi)
{
    #pragma unroll
    for (int k = 0; k < 8; ++k) {
        const v2f ar = A.re[k], ai = A.im[k], br = B.re[k], bi = B.im[k];
        const v2f par = lxor2<LM>(ar), pai = lxor2<LM>(ai);
        const v2f pbr = lxor2<LM>(br), pbi = lxor2<LM>(bi);
        A.re[k] = cAr*ar - cAi*ai + cBr*par - cBi*pai;
        A.im[k] = cAr*ai + cAi*ar + cBr*pai + cBi*par;
        B.re[k] = cAr*br - cAi*bi + cBr*pbr - cBi*pbi;
        B.im[k] = cAr*bi + cAi*br + cBr*pbi + cBi*pbr;
    }
}

// reg gate on qubit 4/5/6 (pack-xor KM = 4/2/1); g = 8 splatted consts
// [m00r,m00i,m01r,m01i,m10r,m10i,m11r,m11i]
template<int KM>
__device__ __forceinline__ void rot_reg2(St& A, St& B, const v2f* __restrict__ g)
{
    const v2f g0=g[0], g1=g[1], g2=g[2], g3=g[3], g4=g[4], g5=g[5], g6=g[6], g7=g[7];
    #pragma unroll
    for (int k0 = 0; k0 < 8; ++k0) {
        if (!(k0 & KM)) {
            const int k1 = k0 | KM;
            {
                const v2f a_r=A.re[k0], a_i=A.im[k0], b_r=A.re[k1], b_i=A.im[k1];
                A.re[k0] = g0*a_r - g1*a_i + g2*b_r - g3*b_i;
                A.im[k0] = g0*a_i + g1*a_r + g2*b_i + g3*b_r;
                A.re[k1] = g4*a_r - g5*a_i + g6*b_r - g7*b_i;
                A.im[k1] = g4*a_i + g5*a_r + g6*b_i + g7*b_r;
            }
            {
                const v2f a_r=B.re[k0], a_i=B.im[k0], b_r=B.re[k1], b_i=B.im[k1];
                B.re[k0] = g0*a_r - g1*a_i + g2*b_r - g3*b_i;
                B.im[k0] = g0*a_i + g1*a_r + g2*b_i + g3*b_r;
                B.re[k1] = g4*a_r - g5*a_i + g6*b_r - g7*b_i;
                B.im[k1] = g4*a_i + g5*a_r + g6*b_i + g7*b_r;
            }
        }
    }
}

// reg gate on qubit 7 (intra-pack). D=(m00,m11) diag, O=(m01,m10) offdiag, packed per-half.
__device__ __forceinline__ void rot_reg7(St& A, St& B, v2f Dr, v2f Di, v2f Or, v2f Oi)
{
    #pragma unroll
    for (int k = 0; k < 8; ++k) {
        {
            const v2f r = A.re[k], i = A.im[k], rs = sw2(r), is = sw2(i);
            A.re[k] = Dr*r - Di*i + Or*rs - Oi*is;
            A.im[k] = Dr*i + Di*r + Or*is + Oi*rs;
        }
        {
            const v2f r = B.re[k], i = B.im[k], rs = sw2(r), is = sw2(i);
            B.re[k] = Dr*r - Di*i + Or*rs - Oi*is;
            B.im[k] = Dr*i + Di*r + Or*is + Oi*rs;
        }
    }
}

template<int BASE>
__device__ __forceinline__ void rot_layer(St& A, St& B, const v2f (*GS)[8], int ll)
{
    { const v2f* g = GS[BASE+0]; const bool hi = (ll>>3)&1;
      rot_lane<8>(A,B, hi?g[6]:g[0], hi?g[7]:g[1], hi?g[4]:g[2], hi?g[5]:g[3]); }
    { const v2f* g = GS[BASE+1]; const bool hi = (ll>>2)&1;
      rot_lane<4>(A,B, hi?g[6]:g[0], hi?g[7]:g[1], hi?g[4]:g[2], hi?g[5]:g[3]); }
    { const v2f* g = GS[BASE+2]; const bool hi = (ll>>1)&1;
      rot_lane<2>(A,B, hi?g[6]:g[0], hi?g[7]:g[1], hi?g[4]:g[2], hi?g[5]:g[3]); }
    { const v2f* g = GS[BASE+3]; const bool hi = ll&1;
      rot_lane<1>(A,B, hi?g[6]:g[0], hi?g[7]:g[1], hi?g[4]:g[2], hi?g[5]:g[3]); }
    rot_reg2<4>(A,B, GS[BASE+4]);
    rot_reg2<2>(A,B, GS[BASE+5]);
    rot_reg2<1>(A,B, GS[BASE+6]);
    { const v2f* g = GS[BASE+7]; rot_reg7(A,B, g[0], g[1], g[2], g[3]); }
}

// ---------------- CNOT primitives (SoA-pair) ----------------
// (AA) ctrl lane bit cb, tgt lane (LM)
template<int LM>
__device__ __forceinline__ void cnAA(St& S, bool cb) {
    #pragma unroll
    for (int k = 0; k < 8; ++k) {
        const v2f pr = lxor2<LM>(S.re[k]), pi = lxor2<LM>(S.im[k]);
        S.re[k] = cb ? pr : S.re[k];
        S.im[k] = cb ? pi : S.im[k];
    }
}
// (AB) ctrl lane bit cb, tgt pack-bit KM: conditional pack swap
template<int KM>
__device__ __forceinline__ void cnAB(St& S, bool cb) {
    #pragma unroll
    for (int k0 = 0; k0 < 8; ++k0) {
        if (!(k0 & KM)) {
            const int k1 = k0 | KM;
            const v2f r0=S.re[k0], r1=S.re[k1], i0=S.im[k0], i1=S.im[k1];
            S.re[k0] = cb ? r1 : r0;  S.re[k1] = cb ? r0 : r1;
            S.im[k0] = cb ? i1 : i0;  S.im[k1] = cb ? i0 : i1;
        }
    }
}
// (D) ctrl pack-bit KM, tgt lane LM: unconditional lane-xor on half the packs
template<int KM, int LM>
__device__ __forceinline__ void cnD(St& S) {
    #pragma unroll
    for (int k = 0; k < 8; ++k)
        if (k & KM) { S.re[k] = lxor2<LM>(S.re[k]); S.im[k] = lxor2<LM>(S.im[k]); }
}
// (E) ctrl qubit7 (odd slots = .y halves), tgt lane LM
template<int LM>
__device__ __forceinline__ void cnE(St& S) {
    #pragma unroll
    for (int k = 0; k < 8; ++k) {
        S.re[k].y = lxorf<LM>(S.re[k].y);
        S.im[k].y = lxorf<LM>(S.im[k].y);
    }
}
// (F) ctrl pack-bit KM, tgt pack-bit KT: static pack swap (free rename)
template<int KM, int KT>
__device__ __forceinline__ void cnF(St& S) {
    #pragma unroll
    for (int k0 = 0; k0 < 8; ++k0) {
        if ((k0 & KM) && !(k0 & KT)) {
            const int k1 = k0 | KT;
            v2f t = S.re[k0]; S.re[k0] = S.re[k1]; S.re[k1] = t;
            t = S.im[k0]; S.im[k0] = S.im[k1]; S.im[k1] = t;
        }
    }
}
// (G) ctrl pack-bit KM, tgt qubit7: intra-pack half swap on half the packs
template<int KM>
__device__ __forceinline__ void cnG(St& S) {
    #pragma unroll
    for (int k = 0; k < 8; ++k)
        if (k & KM) { S.re[k] = sw2(S.re[k]); S.im[k] = sw2(S.im[k]); }
}

// CNOT rings (gates applied in reference order i=0..7, CNOT(i,(i+r)%8))
__device__ __forceinline__ void ring1(St& S, int ll) {   // r=1
    cnAA<4>(S, (ll>>3)&1);   // (0,1)
    cnAA<2>(S, (ll>>2)&1);   // (1,2)
    cnAA<1>(S, (ll>>1)&1);   // (2,3)
    cnAB<4>(S,  ll    &1);   // (3,4)
    cnF<4,2>(S);             // (4,5)
    cnF<2,1>(S);             // (5,6)
    cnG<1>(S);               // (6,7)
    cnE<8>(S);               // (7,0)
}
__device__ __forceinline__ void ring2(St& S, int ll) {   // r=2
    cnAA<2>(S, (ll>>3)&1);   // (0,2)
    cnAA<1>(S, (ll>>2)&1);   // (1,3)
    cnAB<4>(S, (ll>>1)&1);   // (2,4)
    cnAB<2>(S,  ll    &1);   // (3,5)
    cnF<4,1>(S);             // (4,6)
    cnG<2>(S);               // (5,7)
    cnD<1,8>(S);             // (6,0)
    cnE<4>(S);               // (7,1)
}
__device__ __forceinline__ void ring3(St& S, int ll) {   // r=3
    cnAA<1>(S, (ll>>3)&1);   // (0,3)
    cnAB<4>(S, (ll>>2)&1);   // (1,4)
    cnAB<2>(S, (ll>>1)&1);   // (2,5)
    cnAB<1>(S,  ll    &1);   // (3,6)
    cnG<4>(S);               // (4,7)
    cnD<2,8>(S);             // (5,0)
    cnD<1,4>(S);             // (6,1)
    cnE<2>(S);               // (7,2)
}

// ---- init: product state (Rot_rep0_i · RX(x_i)) |0>, packed SoA-pair ----
__device__ __forceinline__ void init_state(const float* __restrict__ xp,
                                           const v2f (*Gc)[4], int ll, St& S)
{
    const float4 xv0 = *reinterpret_cast<const float4*>(xp);
    const float4 xv1 = *reinterpret_cast<const float4*>(xp + 4);
    const float xs[8] = {xv0.x, xv0.y, xv0.z, xv0.w, xv1.x, xv1.y, xv1.z, xv1.w};
    const int b0 = (ll >> 3) & 1, b1_ = (ll >> 2) & 1, b2_ = (ll >> 1) & 1, b3 = ll & 1;

    v2f w0v[8], w1v[8];
    #pragma unroll
    for (int i = 0; i < 8; ++i) {
        float sx, cx;
        __sincosf(0.5f * xs[i], &sx, &cx);
        const v2f m00 = Gc[i][0], m01 = Gc[i][1], m10 = Gc[i][2], m11 = Gc[i][3];
        w0v[i].x = fmaf(cx, m00.x,  sx * m01.y);
        w0v[i].y = fmaf(cx, m00.y, -(sx * m01.x));
        w1v[i].x = fmaf(cx, m10.x,  sx * m11.y);
        w1v[i].y = fmaf(cx, m10.y, -(sx * m11.x));
    }

    // lane-part product over qubits 0..3 (AoS complex)
    v2f L = b0 ? w1v[0] : w0v[0];
    {
        const v2f f = b1_ ? w1v[1] : w0v[1];
        v2f t; t.x = fmaf(L.x, f.x, -(L.y*f.y)); t.y = fmaf(L.x, f.y, L.y*f.x); L = t;
    }
    {
        const v2f f = b2_ ? w1v[2] : w0v[2];
        v2f t; t.x = fmaf(L.x, f.x, -(L.y*f.y)); t.y = fmaf(L.x, f.y, L.y*f.x); L = t;
    }
    {
        const v2f f = b3 ? w1v[3] : w0v[3];
        v2f t; t.x = fmaf(L.x, f.x, -(L.y*f.y)); t.y = fmaf(L.x, f.y, L.y*f.x); L = t;
    }

    v2f p45[4], p67[4];
    #pragma unroll
    for (int a = 0; a < 4; ++a) {
        const int bh = (a >> 1) & 1, bl = a & 1;
        const v2f u = bh ? w1v[4] : w0v[4], v = bl ? w1v[5] : w0v[5];
        p45[a].x = fmaf(u.x, v.x, -(u.y*v.y)); p45[a].y = fmaf(u.x, v.y, u.y*v.x);
        const v2f u2 = bh ? w1v[6] : w0v[6], v2 = bl ? w1v[7] : w0v[7];
        p67[a].x = fmaf(u2.x, v2.x, -(u2.y*v2.y)); p67[a].y = fmaf(u2.x, v2.y, u2.y*v2.x);
    }
    v2f L45[4];
    #pragma unroll
    for (int a = 0; a < 4; ++a) {
        L45[a].x = fmaf(L.x, p45[a].x, -(L.y*p45[a].y));
        L45[a].y = fmaf(L.x, p45[a].y,   L.y*p45[a].x);
    }
    // slot-pair packs for qubits 6,7: P67r[j] = (p67[2j].re, p67[2j+1].re)
    v2f P67r[2], P67i[2];
    P67r[0].x = p67[0].x; P67r[0].y = p67[1].x;
    P67i[0].x = p67[0].y; P67i[0].y = p67[1].y;
    P67r[1].x = p67[2].x; P67r[1].y = p67[3].x;
    P67i[1].x = p67[2].y; P67i[1].y = p67[3].y;

    #pragma unroll
    for (int k = 0; k < 8; ++k) {
        const int a = k >> 1, j = k & 1;
        S.re[k] = L45[a].x * P67r[j] - L45[a].y * P67i[j];
        S.im[k] = L45[a].x * P67i[j] + L45[a].y * P67r[j];
    }
}

// --- slot-space signed sums Sm = sum_r sign(r&m) p[r] ---
__device__ __forceinline__ void slot_wht(const St& S,
                                         float& S1, float& S2, float& S4, float& S8)
{
    float e[8], d[8];
    #pragma unroll
    for (int k = 0; k < 8; ++k) {
        const v2f P = S.re[k]*S.re[k] + S.im[k]*S.im[k];
        e[k] = P.x + P.y;
        d[k] = P.x - P.y;
    }
    S1 = ((d[0]+d[1]) + (d[2]+d[3])) + ((d[4]+d[5]) + (d[6]+d[7]));
    float f[4];
    S2 = 0.f;
    #pragma unroll
    for (int i = 0; i < 4; ++i) { f[i] = e[2*i] + e[2*i+1]; S2 += e[2*i] - e[2*i+1]; }
    S4 = (f[0] - f[1]) + (f[2] - f[3]);
    S8 = (f[0] + f[1]) - (f[2] + f[3]);
}

// --- 16-lane butterfly: zp = sum_ll S ; zs = sum_ll sign(ll&M) S ---
template<int M>
__device__ __forceinline__ void bfly(float S, int ll, float& zp, float& zs)
{
    float v = S;
    if constexpr (M != 1) v += lxorf<1>(v);
    if constexpr (M != 2) v += lxorf<2>(v);
    if constexpr (M != 4) v += lxorf<4>(v);
    if constexpr (M != 8) v += lxorf<8>(v);
    const float t = lxorf<M>(v);
    zp = v + t;
    const float dd = v - t;
    zs = (ll & M) ? -dd : dd;
}

__global__ void __launch_bounds__(256)
qae_fused(const float* __restrict__ x, const float* __restrict__ qw,
          const float* __restrict__ w1, const float* __restrict__ b1,
          const float* __restrict__ w2, const float* __restrict__ b2,
          float* __restrict__ out, int nsamp)
{
    __shared__ __align__(16) v2f GS[24][8];   // layers 1..3, 8 gates, splatted consts
    __shared__ __align__(16) v2f Gc[8][4];    // rep-0 gates, plain complex (init)
    const int tid = threadIdx.x;

    if (tid < 32) {
        const int qrow = (tid < 24) ? (8 + tid) : (tid - 24);   // 8..31 or 0..7
        const float phi = qw[qrow*3+0], th = qw[qrow*3+1], om = qw[qrow*3+2];
        float s, c, sp, cp, sm, cm;
        sincosf(0.5f*th,       &s,  &c);
        sincosf(0.5f*(phi+om), &sp, &cp);
        sincosf(0.5f*(phi-om), &sm, &cm);
        const float m00r =  cp*c, m00i = -sp*c;
        const float m01r = -cm*s, m01i = -sm*s;
        const float m10r =  cm*s, m10i = -sm*s;
        const float m11r =  cp*c, m11i =  sp*c;
        if (tid < 24) {
            v2f t;
            if ((tid & 7) == 7) {   // qubit-7 gate: pack D=(m00,m11), O=(m01,m10)
                t.x=m00r; t.y=m11r; GS[tid][0]=t;
                t.x=m00i; t.y=m11i; GS[tid][1]=t;
                t.x=m01r; t.y=m10r; GS[tid][2]=t;
                t.x=m01i; t.y=m10i; GS[tid][3]=t;
                t.x=0.f;  t.y=0.f;  GS[tid][4]=t; GS[tid][5]=t; GS[tid][6]=t; GS[tid][7]=t;
            } else {                // splatted
                t.x=m00r; t.y=m00r; GS[tid][0]=t;
                t.x=m00i; t.y=m00i; GS[tid][1]=t;
                t.x=m01r; t.y=m01r; GS[tid][2]=t;
                t.x=m01i; t.y=m01i; GS[tid][3]=t;
                t.x=m10r; t.y=m10r; GS[tid][4]=t;
                t.x=m10i; t.y=m10i; GS[tid][5]=t;
                t.x=m11r; t.y=m11r; GS[tid][6]=t;
                t.x=m11i; t.y=m11i; GS[tid][7]=t;
            }
        } else {
            v2f t;
            const int i = tid - 24;
            t.x=m00r; t.y=m00i; Gc[i][0]=t;
            t.x=m01r; t.y=m01i; Gc[i][1]=t;
            t.x=m10r; t.y=m10i; Gc[i][2]=t;
            t.x=m11r; t.y=m11i; Gc[i][3]=t;
        }
    }
    __syncthreads();

    const int group = (blockIdx.x * 256 + tid) >> 4;
    const int sA = group * 2;
    if (sA >= nsamp) return;
    const int ll = tid & 15;

    St A, B;
    init_state(x + (size_t)sA * 8,     Gc, ll, A);
    init_state(x + (size_t)sA * 8 + 8, Gc, ll, B);

    ring1(A, ll); ring1(B, ll);
    rot_layer<0>(A, B, GS, ll);
    ring2(A, ll); ring2(B, ll);
    rot_layer<8>(A, B, GS, ll);
    ring3(A, ll); ring3(B, ll);
    rot_layer<16>(A, B, GS, ll);
    // ring4 folded into readout sign masks

    float S1a, S2a, S4a, S8a, S1b, S2b, S4b, S8b;
    slot_wht(A, S1a, S2a, S4a, S8a);
    slot_wht(B, S1b, S2b, S4b, S8b);

    float zA[8], zB[8];
    bfly<8>(S8a, ll, zA[0], zA[4]);
    bfly<4>(S4a, ll, zA[1], zA[5]);
    bfly<2>(S2a, ll, zA[2], zA[6]);
    bfly<1>(S1a, ll, zA[3], zA[7]);
    bfly<8>(S8b, ll, zB[0], zB[4]);
    bfly<4>(S4b, ll, zB[1], zB[5]);
    bfly<2>(S2b, ll, zB[2], zB[6]);
    bfly<1>(S1b, ll, zB[3], zB[7]);

    // lanes 0-7 -> sample A, lanes 8-15 -> sample B
    float zs[8];
    #pragma unroll
    for (int i = 0; i < 8; ++i) zs[i] = (ll < 8) ? zA[i] : zB[i];

    const int col = ll & 7;
    float h0 = b1[0], h1 = b1[1], h2 = b1[2], h3 = b1[3];
    #pragma unroll
    for (int i = 0; i < 8; ++i) {
        h0 += zs[i] * w1[i];
        h1 += zs[i] * w1[8 + i];
        h2 += zs[i] * w1[16 + i];
        h3 += zs[i] * w1[24 + i];
    }
    h0 = fmaxf(h0, 0.f); h1 = fmaxf(h1, 0.f);
    h2 = fmaxf(h2, 0.f); h3 = fmaxf(h3, 0.f);
    const float o = b2[col] + h0*w2[col*4+0] + h1*w2[col*4+1]
                            + h2*w2[col*4+2] + h3*w2[col*4+3];
    out[(size_t)(sA + (ll >> 3)) * 8 + col] = o;
}

extern "C" void kernel_launch(void* const* d_in, const int* in_sizes, int n_in,
                              void* d_out, int out_size, void* d_ws, size_t ws_size,
                              hipStream_t stream)
{
    const float* x  = (const float*)d_in[0];
    const float* qw = (const float*)d_in[1];
    const float* w1 = (const float*)d_in[2];
    const float* b1 = (const float*)d_in[3];
    const float* w2 = (const float*)d_in[4];
    const float* b2 = (const float*)d_in[5];
    float* out = (float*)d_out;

    const int nsamp  = in_sizes[0] / 8;             // 65536
    const int groups = (nsamp + 1) / 2;             // 2 samples per 16-lane group
    const int total_threads = groups * 16;
    const int blocks = (total_threads + 255) / 256; // 2048

    hipLaunchKernelGGL(qae_fused, dim3(blocks), dim3(256), 0, stream,
                       x, qw, w1, b1, w2, b2, out, nsamp);
}

// Round 6
// 69.469 us; speedup vs baseline: 1.3575x; 1.3575x over previous
//
#include <hip/hip_runtime.h>
#include <math.h>

// Layout: sample = 16 lanes x 16 slots; 1 sample per 16-lane group. SoA slot-pair packs:
//   pack k (k=0..7) holds slots (2k,2k+1); Re[k]=(re[2k],re[2k+1]), Im[k] likewise.
// Qubit q in 0..3 -> lane bit (3-q) of (tid&15)
// Qubit 4 -> pack bit2, qubit 5 -> pack bit1, qubit 6 -> pack bit0, qubit 7 -> intra-pack half.
// Rot(phi,theta,omega) = Rz(omega)·Ry(theta)·Rz(phi)  [matches reference matrix].
// Circuit restructured as:
//   init(RX + full Rot layer0 folded, product state)
//   ring1 -> DiagA(=Dphi1) -> Ry1
//   ring2 -> DiagB(=Domega1 pushed through ring2, * Dphi2) -> Ry2
//   ring3 -> DiagC(=Domega2 pushed through ring3, * Dphi3) -> Ry3
//   [Domega3 dropped (|.|^2 readout), ring4 folded into readout sign masks]
// Diagonal tables (256 complex each) built once per block in LDS.

typedef float v2f __attribute__((ext_vector_type(2)));

// ---- cross-lane xor within 16-lane rows (verified primitives, unchanged) ----
template<int CTRL>
__device__ __forceinline__ float dppf(float v) {
    const int i = __float_as_int(v);
    return __int_as_float(__builtin_amdgcn_update_dpp(i, i, CTRL, 0xF, 0xF, true));
}
template<int M>
__device__ __forceinline__ float lxorf(float v) {
    static_assert(M == 1 || M == 2 || M == 4 || M == 8, "bad mask");
    if constexpr (M == 1)      return dppf<0xB1>(v);   // quad_perm [1,0,3,2]
    else if constexpr (M == 2) return dppf<0x4E>(v);   // quad_perm [2,3,0,1]
    else if constexpr (M == 4) return __int_as_float(__builtin_amdgcn_ds_swizzle(__float_as_int(v), 0x101F));
    else                       return __int_as_float(__builtin_amdgcn_ds_swizzle(__float_as_int(v), 0x201F));
}
template<int M>
__device__ __forceinline__ v2f lxor2(v2f v) {
    v2f r; r.x = lxorf<M>(v.x); r.y = lxorf<M>(v.y); return r;
}
__device__ __forceinline__ v2f vsplat(float f) { v2f v; v.x = f; v.y = f; return v; }

struct St { v2f re[8]; v2f im[8]; };

// ---------------- Ry gates ----------------
// lane qubit (LM = 8,4,2,1): new = c*mine + t*partner, t = (bit ? +s : -s)
template<int LM>
__device__ __forceinline__ void ry_lane(St& S, float c, float t) {
    const v2f cv = vsplat(c), tv = vsplat(t);
    #pragma unroll
    for (int k = 0; k < 8; ++k) {
        const v2f pr = lxor2<LM>(S.re[k]);
        const v2f pi = lxor2<LM>(S.im[k]);
        S.re[k] = cv * S.re[k] + tv * pr;
        S.im[k] = cv * S.im[k] + tv * pi;
    }
}
// reg qubit 4/5/6 (pack-xor KM = 4/2/1): a0' = c a0 - s a1 ; a1' = s a0 + c a1
template<int KM>
__device__ __forceinline__ void ry_reg(St& S, float c, float s) {
    const v2f cv = vsplat(c), sv = vsplat(s);
    #pragma unroll
    for (int k0 = 0; k0 < 8; ++k0) {
        if (!(k0 & KM)) {
            const int k1 = k0 | KM;
            const v2f r0 = S.re[k0], r1 = S.re[k1];
            S.re[k0] = cv * r0 - sv * r1;
            S.re[k1] = sv * r0 + cv * r1;
            const v2f i0 = S.im[k0], i1 = S.im[k1];
            S.im[k0] = cv * i0 - sv * i1;
            S.im[k1] = sv * i0 + cv * i1;
        }
    }
}
// qubit 7 (intra-pack): x' = c x - s y ; y' = s x + c y
__device__ __forceinline__ void ry_q7(St& S, float c, float s) {
    #pragma unroll
    for (int k = 0; k < 8; ++k) {
        const v2f r = S.re[k], i = S.im[k];
        v2f nr, ni;
        nr.x = c * r.x - s * r.y;  nr.y = s * r.x + c * r.y;
        ni.x = c * i.x - s * i.y;  ni.y = s * i.x + c * i.y;
        S.re[k] = nr; S.im[k] = ni;
    }
}

__device__ __forceinline__ void ry_layer(St& S, int ll, const v2f* __restrict__ cs) {
    { const v2f g = cs[0]; ry_lane<8>(S, g.x, ((ll >> 3) & 1) ? g.y : -g.y); }
    { const v2f g = cs[1]; ry_lane<4>(S, g.x, ((ll >> 2) & 1) ? g.y : -g.y); }
    { const v2f g = cs[2]; ry_lane<2>(S, g.x, ((ll >> 1) & 1) ? g.y : -g.y); }
    { const v2f g = cs[3]; ry_lane<1>(S, g.x, ( ll       & 1) ? g.y : -g.y); }
    { const v2f g = cs[4]; ry_reg<4>(S, g.x, g.y); }
    { const v2f g = cs[5]; ry_reg<2>(S, g.x, g.y); }
    { const v2f g = cs[6]; ry_reg<1>(S, g.x, g.y); }
    { const v2f g = cs[7]; ry_q7 (S, g.x, g.y); }
}

// ---------------- diagonal apply: amp *= e^{i a}, tables SoA padded stride 20 ----------------
__device__ __forceinline__ void diag_apply(St& S, const float* __restrict__ dre,
                                           const float* __restrict__ dim_, int ll) {
    const float4* pr = reinterpret_cast<const float4*>(dre  + ll * 20);
    const float4* pi = reinterpret_cast<const float4*>(dim_ + ll * 20);
    #pragma unroll
    for (int j = 0; j < 4; ++j) {
        const float4 r4 = pr[j], i4 = pi[j];
        v2f dr0; dr0.x = r4.x; dr0.y = r4.y;
        v2f dr1; dr1.x = r4.z; dr1.y = r4.w;
        v2f di0; di0.x = i4.x; di0.y = i4.y;
        v2f di1; di1.x = i4.z; di1.y = i4.w;
        const int k0 = 2 * j, k1 = 2 * j + 1;
        const v2f re0 = S.re[k0], im0 = S.im[k0];
        S.re[k0] = dr0 * re0 - di0 * im0;
        S.im[k0] = dr0 * im0 + di0 * re0;
        const v2f re1 = S.re[k1], im1 = S.im[k1];
        S.re[k1] = dr1 * re1 - di1 * im1;
        S.im[k1] = dr1 * im1 + di1 * re1;
    }
}

// ---------------- CNOT primitives (round-5-verified, unchanged) ----------------
template<int LM>
__device__ __forceinline__ void cnAA(St& S, bool cb) {
    #pragma unroll
    for (int k = 0; k < 8; ++k) {
        const v2f pr = lxor2<LM>(S.re[k]), pi = lxor2<LM>(S.im[k]);
        S.re[k] = cb ? pr : S.re[k];
        S.im[k] = cb ? pi : S.im[k];
    }
}
template<int KM>
__device__ __forceinline__ void cnAB(St& S, bool cb) {
    #pragma unroll
    for (int k0 = 0; k0 < 8; ++k0) {
        if (!(k0 & KM)) {
            const int k1 = k0 | KM;
            const v2f r0 = S.re[k0], r1 = S.re[k1], i0 = S.im[k0], i1 = S.im[k1];
            S.re[k0] = cb ? r1 : r0;  S.re[k1] = cb ? r0 : r1;
            S.im[k0] = cb ? i1 : i0;  S.im[k1] = cb ? i0 : i1;
        }
    }
}
template<int KM, int LM>
__device__ __forceinline__ void cnD(St& S) {
    #pragma unroll
    for (int k = 0; k < 8; ++k)
        if (k & KM) { S.re[k] = lxor2<LM>(S.re[k]); S.im[k] = lxor2<LM>(S.im[k]); }
}
template<int LM>
__device__ __forceinline__ void cnE(St& S) {
    #pragma unroll
    for (int k = 0; k < 8; ++k) {
        S.re[k].y = lxorf<LM>(S.re[k].y);
        S.im[k].y = lxorf<LM>(S.im[k].y);
    }
}
template<int KM, int KT>
__device__ __forceinline__ void cnF(St& S) {
    #pragma unroll
    for (int k0 = 0; k0 < 8; ++k0) {
        if ((k0 & KM) && !(k0 & KT)) {
            const int k1 = k0 | KT;
            v2f t = S.re[k0]; S.re[k0] = S.re[k1]; S.re[k1] = t;
            t = S.im[k0]; S.im[k0] = S.im[k1]; S.im[k1] = t;
        }
    }
}
__device__ __forceinline__ v2f sw2(v2f v) { return __builtin_shufflevector(v, v, 1, 0); }
template<int KM>
__device__ __forceinline__ void cnG(St& S) {
    #pragma unroll
    for (int k = 0; k < 8; ++k)
        if (k & KM) { S.re[k] = sw2(S.re[k]); S.im[k] = sw2(S.im[k]); }
}

__device__ __forceinline__ void ring1(St& S, int ll) {   // r=1
    cnAA<4>(S, (ll >> 3) & 1);
    cnAA<2>(S, (ll >> 2) & 1);
    cnAA<1>(S, (ll >> 1) & 1);
    cnAB<4>(S,  ll       & 1);
    cnF<4, 2>(S);
    cnF<2, 1>(S);
    cnG<1>(S);
    cnE<8>(S);
}
__device__ __forceinline__ void ring2(St& S, int ll) {   // r=2
    cnAA<2>(S, (ll >> 3) & 1);
    cnAA<1>(S, (ll >> 2) & 1);
    cnAB<4>(S, (ll >> 1) & 1);
    cnAB<2>(S,  ll       & 1);
    cnF<4, 1>(S);
    cnG<2>(S);
    cnD<1, 8>(S);
    cnE<4>(S);
}
__device__ __forceinline__ void ring3(St& S, int ll) {   // r=3
    cnAA<1>(S, (ll >> 3) & 1);
    cnAB<4>(S, (ll >> 2) & 1);
    cnAB<2>(S, (ll >> 1) & 1);
    cnAB<1>(S,  ll       & 1);
    cnG<4>(S);
    cnD<2, 8>(S);
    cnD<1, 4>(S);
    cnE<2>(S);
}

// ---- init: product state (Rot_layer0_i · RX(x_i)) |0>, SoA packs (round-5-verified) ----
__device__ __forceinline__ void init_state(const float* __restrict__ xp,
                                           const v2f (*Gc)[4], int ll, St& S)
{
    const float4 xv0 = *reinterpret_cast<const float4*>(xp);
    const float4 xv1 = *reinterpret_cast<const float4*>(xp + 4);
    const float xs[8] = {xv0.x, xv0.y, xv0.z, xv0.w, xv1.x, xv1.y, xv1.z, xv1.w};
    const int b0 = (ll >> 3) & 1, b1_ = (ll >> 2) & 1, b2_ = (ll >> 1) & 1, b3 = ll & 1;

    v2f w0v[8], w1v[8];
    #pragma unroll
    for (int i = 0; i < 8; ++i) {
        float sx, cx;
        __sincosf(0.5f * xs[i], &sx, &cx);
        const v2f m00 = Gc[i][0], m01 = Gc[i][1], m10 = Gc[i][2], m11 = Gc[i][3];
        w0v[i].x = fmaf(cx, m00.x,  sx * m01.y);
        w0v[i].y = fmaf(cx, m00.y, -(sx * m01.x));
        w1v[i].x = fmaf(cx, m10.x,  sx * m11.y);
        w1v[i].y = fmaf(cx, m10.y, -(sx * m11.x));
    }

    v2f L = b0 ? w1v[0] : w0v[0];
    {
        const v2f f = b1_ ? w1v[1] : w0v[1];
        v2f t; t.x = fmaf(L.x, f.x, -(L.y * f.y)); t.y = fmaf(L.x, f.y, L.y * f.x); L = t;
    }
    {
        const v2f f = b2_ ? w1v[2] : w0v[2];
        v2f t; t.x = fmaf(L.x, f.x, -(L.y * f.y)); t.y = fmaf(L.x, f.y, L.y * f.x); L = t;
    }
    {
        const v2f f = b3 ? w1v[3] : w0v[3];
        v2f t; t.x = fmaf(L.x, f.x, -(L.y * f.y)); t.y = fmaf(L.x, f.y, L.y * f.x); L = t;
    }

    v2f p45[4], p67[4];
    #pragma unroll
    for (int a = 0; a < 4; ++a) {
        const int bh = (a >> 1) & 1, bl = a & 1;
        const v2f u = bh ? w1v[4] : w0v[4], v = bl ? w1v[5] : w0v[5];
        p45[a].x = fmaf(u.x, v.x, -(u.y * v.y)); p45[a].y = fmaf(u.x, v.y, u.y * v.x);
        const v2f u2 = bh ? w1v[6] : w0v[6], v2 = bl ? w1v[7] : w0v[7];
        p67[a].x = fmaf(u2.x, v2.x, -(u2.y * v2.y)); p67[a].y = fmaf(u2.x, v2.y, u2.y * v2.x);
    }
    v2f L45[4];
    #pragma unroll
    for (int a = 0; a < 4; ++a) {
        L45[a].x = fmaf(L.x, p45[a].x, -(L.y * p45[a].y));
        L45[a].y = fmaf(L.x, p45[a].y,   L.y * p45[a].x);
    }
    v2f P67r[2], P67i[2];
    P67r[0].x = p67[0].x; P67r[0].y = p67[1].x;
    P67i[0].x = p67[0].y; P67i[0].y = p67[1].y;
    P67r[1].x = p67[2].x; P67r[1].y = p67[3].x;
    P67i[1].x = p67[2].y; P67i[1].y = p67[3].y;

    #pragma unroll
    for (int k = 0; k < 8; ++k) {
        const int a = k >> 1, j = k & 1;
        S.re[k] = vsplat(L45[a].x) * P67r[j] - vsplat(L45[a].y) * P67i[j];
        S.im[k] = vsplat(L45[a].x) * P67i[j] + vsplat(L45[a].y) * P67r[j];
    }
}

// --- slot-space signed sums Sm = sum_r sign(r&m) p[r] (round-5-verified) ---
__device__ __forceinline__ void slot_wht(const St& S,
                                         float& S1, float& S2, float& S4, float& S8)
{
    float e[8], d[8];
    #pragma unroll
    for (int k = 0; k < 8; ++k) {
        const v2f P = S.re[k] * S.re[k] + S.im[k] * S.im[k];
        e[k] = P.x + P.y;
        d[k] = P.x - P.y;
    }
    S1 = ((d[0] + d[1]) + (d[2] + d[3])) + ((d[4] + d[5]) + (d[6] + d[7]));
    float f[4];
    S2 = 0.f;
    #pragma unroll
    for (int i = 0; i < 4; ++i) { f[i] = e[2*i] + e[2*i+1]; S2 += e[2*i] - e[2*i+1]; }
    S4 = (f[0] - f[1]) + (f[2] - f[3]);
    S8 = (f[0] + f[1]) - (f[2] + f[3]);
}

template<int M>
__device__ __forceinline__ void bfly(float S, int ll, float& zp, float& zs)
{
    float v = S;
    if constexpr (M != 1) v += lxorf<1>(v);
    if constexpr (M != 2) v += lxorf<2>(v);
    if constexpr (M != 4) v += lxorf<4>(v);
    if constexpr (M != 8) v += lxorf<8>(v);
    const float t = lxorf<M>(v);
    zp = v + t;
    const float dd = v - t;
    zs = (ll & M) ? -dd : dd;
}

// forward basis-state map of a CNOT ring with shift r (sequential, updated bits)
__device__ __forceinline__ int ring_perm(int s, int r) {
    #pragma unroll
    for (int i = 0; i < 8; ++i) {
        const int t = (i + r) & 7;
        const int cb = (s >> (7 - i)) & 1;
        s ^= cb << (7 - t);
    }
    return s;
}

__global__ void __launch_bounds__(256)
qae_fused(const float* __restrict__ x, const float* __restrict__ qw,
          const float* __restrict__ w1, const float* __restrict__ b1,
          const float* __restrict__ w2, const float* __restrict__ b2,
          float* __restrict__ out, int nsamp)
{
    // padded diag tables: entry f at (f>>4)*20 + (f&15)
    __shared__ __align__(16) float dAre[320], dAim[320];
    __shared__ __align__(16) float dBre[320], dBim[320];
    __shared__ __align__(16) float dCre[320], dCim[320];
    __shared__ float tmpang[256];
    __shared__ __align__(16) v2f Gc[8][4];    // layer-0 Rot matrices (init)
    __shared__ v2f RyCS[24];                  // (cos(th/2), sin(th/2)) layers 1..3

    const int tid = threadIdx.x;
    const int u = tid;                         // this thread's preamble state index
    const int idxu = ((u >> 4) * 20) + (u & 15);

    // --- preamble: per-state diagonal angles (scalar-uniform qw reads) ---
    float aA = 0.f, aW1 = 0.f, aP2 = 0.f, aW2 = 0.f, aP3 = 0.f;
    #pragma unroll
    for (int i = 0; i < 8; ++i) {
        const float sg = ((u >> (7 - i)) & 1) ? 0.5f : -0.5f;
        aA  += sg * qw[24 + i*3 + 0];   // phi_1
        aW1 += sg * qw[24 + i*3 + 2];   // omega_1
        aP2 += sg * qw[48 + i*3 + 0];   // phi_2
        aW2 += sg * qw[48 + i*3 + 2];   // omega_2
        aP3 += sg * qw[72 + i*3 + 0];   // phi_3
    }
    {
        float s_, c_;
        sincosf(aA, &s_, &c_);
        dAre[idxu] = c_; dAim[idxu] = s_;
    }
    tmpang[ring_perm(u, 2)] = aW1;       // scatter Domega1 through ring2 (bijective)

    if (tid < 24) {                      // Ry constants, layers 1..3
        const int l = 1 + (tid >> 3), i = tid & 7;
        float s_, c_;
        sincosf(0.5f * qw[l*24 + i*3 + 1], &s_, &c_);
        v2f t; t.x = c_; t.y = s_;
        RyCS[tid] = t;
    }
    if (tid >= 32 && tid < 40) {         // layer-0 Rot matrices for init
        const int i = tid - 32;
        const float phi = qw[i*3 + 0], th = qw[i*3 + 1], om = qw[i*3 + 2];
        float s, c, sp, cp, sm, cm;
        sincosf(0.5f * th,         &s,  &c);
        sincosf(0.5f * (phi + om), &sp, &cp);
        sincosf(0.5f * (phi - om), &sm, &cm);
        v2f t;
        t.x =  cp*c; t.y = -sp*c; Gc[i][0] = t;   // m00
        t.x = -cm*s; t.y = -sm*s; Gc[i][1] = t;   // m01
        t.x =  cm*s; t.y = -sm*s; Gc[i][2] = t;   // m10
        t.x =  cp*c; t.y =  sp*c; Gc[i][3] = t;   // m11
    }
    __syncthreads();
    {
        const float aB = tmpang[u] + aP2;
        float s_, c_;
        sincosf(aB, &s_, &c_);
        dBre[idxu] = c_; dBim[idxu] = s_;
    }
    __syncthreads();                      // all reads of tmpang done
    tmpang[ring_perm(u, 3)] = aW2;        // scatter Domega2 through ring3
    __syncthreads();
    {
        const float aC = tmpang[u] + aP3;
        float s_, c_;
        sincosf(aC, &s_, &c_);
        dCre[idxu] = c_; dCim[idxu] = s_;
    }
    __syncthreads();

    const int sample = (blockIdx.x * 256 + tid) >> 4;
    if (sample >= nsamp) return;
    const int ll = tid & 15;

    St S;
    init_state(x + (size_t)sample * 8, Gc, ll, S);

    ring1(S, ll);
    diag_apply(S, dAre, dAim, ll);
    ry_layer(S, ll, RyCS);

    ring2(S, ll);
    diag_apply(S, dBre, dBim, ll);
    ry_layer(S, ll, RyCS + 8);

    ring3(S, ll);
    diag_apply(S, dCre, dCim, ll);
    ry_layer(S, ll, RyCS + 16);
    // Domega3 dropped (phase-invariant readout); ring4 folded into signs below

    float S1, S2, S4, S8;
    slot_wht(S, S1, S2, S4, S8);

    float z[8];
    bfly<8>(S8, ll, z[0], z[4]);
    bfly<4>(S4, ll, z[1], z[5]);
    bfly<2>(S2, ll, z[2], z[6]);
    bfly<1>(S1, ll, z[3], z[7]);

    if (ll < 8) {
        float h0 = b1[0], h1 = b1[1], h2 = b1[2], h3 = b1[3];
        #pragma unroll
        for (int i = 0; i < 8; ++i) {
            h0 += z[i] * w1[i];
            h1 += z[i] * w1[8 + i];
            h2 += z[i] * w1[16 + i];
            h3 += z[i] * w1[24 + i];
        }
        h0 = fmaxf(h0, 0.f); h1 = fmaxf(h1, 0.f);
        h2 = fmaxf(h2, 0.f); h3 = fmaxf(h3, 0.f);
        const float o = b2[ll] + h0*w2[ll*4+0] + h1*w2[ll*4+1]
                                + h2*w2[ll*4+2] + h3*w2[ll*4+3];
        out[(size_t)sample * 8 + ll] = o;
    }
}

extern "C" void kernel_launch(void* const* d_in, const int* in_sizes, int n_in,
                              void* d_out, int out_size, void* d_ws, size_t ws_size,
                              hipStream_t stream)
{
    const float* x  = (const float*)d_in[0];
    const float* qw = (const float*)d_in[1];
    const float* w1 = (const float*)d_in[2];
    const float* b1 = (const float*)d_in[3];
    const float* w2 = (const float*)d_in[4];
    const float* b2 = (const float*)d_in[5];
    float* out = (float*)d_out;

    const int nsamp = in_sizes[0] / 8;              // 65536
    const int total_threads = nsamp * 16;           // 16 lanes per sample
    const int blocks = (total_threads + 255) / 256; // 4096

    hipLaunchKernelGGL(qae_fused, dim3(blocks), dim3(256), 0, stream,
                       x, qw, w1, b1, w2, b2, out, nsamp);
}

// Round 7
// 63.673 us; speedup vs baseline: 1.4810x; 1.0910x over previous
//
#include <hip/hip_runtime.h>
#include <math.h>

// Layout: sample = 16 lanes x 16 slots; 1 sample per 16-lane group.
// State stored as 32 scalar floats re[16], im[16]; state index u = ll*16 + r,
// qubit q <-> bit (7-q) of u (lane bits 7..4 = ll bits 3..0; slot bits 3..0 = r).
//
// CNOT rings are NEVER materialized. Each ring is a GF(2)-linear map t = P u
// (sequential CNOTs with updated controls). We track the accumulated maps
// P1..P4 at COMPILE TIME and pull all later ops back to the storage basis:
//   Ry gate on virtual qubit-bit b at layer l: pair mask m = Pl^{-1} e_b,
//     side dual d = row_b(Pl): new[u] = c*v[u] + (parity(u&d)? +s:-s)*v[u^m].
//   Diag (Rz products): table_l[u] = omega_{l-1}(P_{l-1}u) + phi_l(P_l u).
//   Readout: z_q = sum_u (-1)^{parity(u & row_{7-q}(P4))} |v[u]|^2
//     = slot-FWHT + signed lane butterflies. omega_3 dies in |.|^2.

typedef float v2f __attribute__((ext_vector_type(2)));

// ---------------- constexpr GF(2) machinery ----------------
struct M8 { unsigned char r[8]; };   // t_b = parity(r[b] & u)

constexpr M8 ident8() {
    M8 m{};
    for (int b = 0; b < 8; ++b) m.r[b] = (unsigned char)(1u << b);
    return m;
}
// ring with shift s: CNOT(ctrl qubit i, tgt (i+s)%8), i=0..7 sequential (updated ctrl)
constexpr M8 ring_mat(M8 m, int s) {
    for (int i = 0; i < 8; ++i) {
        const int cb = 7 - i, tb = 7 - ((i + s) & 7);
        m.r[tb] = (unsigned char)(m.r[tb] ^ m.r[cb]);
    }
    return m;
}
constexpr M8 inv8(M8 a) {
    M8 inv = ident8();
    for (int col = 0; col < 8; ++col) {
        int piv = col;
        while (!((a.r[piv] >> col) & 1)) ++piv;
        unsigned char t = a.r[piv]; a.r[piv] = a.r[col]; a.r[col] = t;
        t = inv.r[piv]; inv.r[piv] = inv.r[col]; inv.r[col] = t;
        for (int q = 0; q < 8; ++q)
            if (q != col && ((a.r[q] >> col) & 1)) {
                a.r[q] = (unsigned char)(a.r[q] ^ a.r[col]);
                inv.r[q] = (unsigned char)(inv.r[q] ^ inv.r[col]);
            }
    }
    return inv;
}
constexpr int mask_of(M8 inv, int b) {   // P^{-1} e_b
    int m = 0;
    for (int j = 0; j < 8; ++j) m |= ((inv.r[j] >> b) & 1) << j;
    return m;
}

constexpr M8 P1c  = ring_mat(ident8(), 1);
constexpr M8 P2c  = ring_mat(P1c, 2);
constexpr M8 P3c  = ring_mat(P2c, 3);
constexpr M8 P4c  = ring_mat(P3c, 4);
constexpr M8 P1ic = inv8(P1c);
constexpr M8 P2ic = inv8(P2c);
constexpr M8 P3ic = inv8(P3c);

// ---------------- cross-lane xor within 16-lane rows ----------------
template<int CTRL>
__device__ __forceinline__ float dppf(float v) {
    const int i = __float_as_int(v);
    return __int_as_float(__builtin_amdgcn_update_dpp(i, i, CTRL, 0xF, 0xF, true));
}
template<int M>
__device__ __forceinline__ float lxorf(float v) {
    static_assert(M >= 1 && M <= 15, "bad mask");
    if constexpr (M == 1)      return dppf<0xB1>(v);   // quad_perm [1,0,3,2]
    else if constexpr (M == 2) return dppf<0x4E>(v);   // quad_perm [2,3,0,1]
    else if constexpr (M == 3) return dppf<0x1B>(v);   // quad_perm [3,2,1,0]
    else return __int_as_float(__builtin_amdgcn_ds_swizzle(__float_as_int(v), (M << 10) | 0x1F));
}

// ---------------- generalized Ry gate ----------------
template<int MASK, int DUAL>
__device__ __forceinline__ void gry(float (&re)[16], float (&im)[16], int ll, v2f cs)
{
    constexpr int ml = (MASK >> 4) & 15, ms = MASK & 15;
    constexpr int dl = (DUAL >> 4) & 15, ds = DUAL & 15;
    const float c = cs.x, s = cs.y;
    float tp;
    if constexpr (dl != 0) {
        int t = ll & dl; t ^= t >> 2; t ^= t >> 1;
        tp = (t & 1) ? s : -s;      // coef where parity(r&ds)==0
    } else {
        tp = -s;
    }
    const float tn = -tp;
    if constexpr (ms == 0) {
        #pragma unroll
        for (int r = 0; r < 16; ++r) {
            int pp = r & ds; pp ^= pp >> 2; pp ^= pp >> 1;     // folds (r literal)
            const float tr = (pp & 1) ? tn : tp;
            re[r] = fmaf(tr, lxorf<ml>(re[r]), c * re[r]);
            im[r] = fmaf(tr, lxorf<ml>(im[r]), c * im[r]);
        }
    } else {
        constexpr int lo = ms & (-ms);
        #pragma unroll
        for (int r0 = 0; r0 < 16; ++r0) {
            if ((r0 & lo) == 0) {
                const int r1 = r0 ^ ms;
                int p0 = r0 & ds; p0 ^= p0 >> 2; p0 ^= p0 >> 1;
                int p1 = r1 & ds; p1 ^= p1 >> 2; p1 ^= p1 >> 1;
                const float t0 = (p0 & 1) ? tn : tp;
                const float t1 = (p1 & 1) ? tn : tp;
                float q0r, q0i, q1r, q1i;
                if constexpr (ml != 0) {
                    q0r = lxorf<ml>(re[r1]); q0i = lxorf<ml>(im[r1]);
                    q1r = lxorf<ml>(re[r0]); q1i = lxorf<ml>(im[r0]);
                } else {
                    q0r = re[r1]; q0i = im[r1];
                    q1r = re[r0]; q1i = im[r0];
                }
                const float n0r = fmaf(t0, q0r, c * re[r0]);
                const float n0i = fmaf(t0, q0i, c * im[r0]);
                const float n1r = fmaf(t1, q1r, c * re[r1]);
                const float n1i = fmaf(t1, q1i, c * im[r1]);
                re[r0] = n0r; im[r0] = n0i;
                re[r1] = n1r; im[r1] = n1i;
            }
        }
    }
}

template<int L>   // L = 1,2,3
__device__ __forceinline__ void gry_layer(float (&re)[16], float (&im)[16], int ll,
                                          const v2f* __restrict__ cs)
{
    constexpr M8 P  = (L == 1) ? P1c  : (L == 2) ? P2c  : P3c;
    constexpr M8 Pi = (L == 1) ? P1ic : (L == 2) ? P2ic : P3ic;
    gry<mask_of(Pi, 7), P.r[7]>(re, im, ll, cs[0]);   // qubit 0
    gry<mask_of(Pi, 6), P.r[6]>(re, im, ll, cs[1]);
    gry<mask_of(Pi, 5), P.r[5]>(re, im, ll, cs[2]);
    gry<mask_of(Pi, 4), P.r[4]>(re, im, ll, cs[3]);
    gry<mask_of(Pi, 3), P.r[3]>(re, im, ll, cs[4]);
    gry<mask_of(Pi, 2), P.r[2]>(re, im, ll, cs[5]);
    gry<mask_of(Pi, 1), P.r[1]>(re, im, ll, cs[6]);
    gry<mask_of(Pi, 0), P.r[0]>(re, im, ll, cs[7]);   // qubit 7
}

// ---------------- diagonal apply (interleaved re,im; row stride 36 floats) ----------------
__device__ __forceinline__ void diag_apply(float (&re)[16], float (&im)[16],
                                           const float* __restrict__ tab, int ll)
{
    const float4* p4 = reinterpret_cast<const float4*>(tab + ll * 36);
    #pragma unroll
    for (int j = 0; j < 8; ++j) {
        const float4 v = p4[j];           // (re0,im0,re1,im1) for slots 2j,2j+1
        const int r0 = 2 * j, r1 = 2 * j + 1;
        float nr = v.x * re[r0] - v.y * im[r0];
        float ni = v.x * im[r0] + v.y * re[r0];
        re[r0] = nr; im[r0] = ni;
        nr = v.z * re[r1] - v.w * im[r1];
        ni = v.z * im[r1] + v.w * re[r1];
        re[r1] = nr; im[r1] = ni;
    }
}

// ---- init: product state (Rot_layer0_i · RX(x_i)) |0> (round-3/6-verified math) ----
__device__ __forceinline__ void init_state(const float* __restrict__ xp,
                                           const v2f (*Gc)[4], int ll,
                                           float (&re)[16], float (&im)[16])
{
    const float4 xv0 = *reinterpret_cast<const float4*>(xp);
    const float4 xv1 = *reinterpret_cast<const float4*>(xp + 4);
    const float xs[8] = {xv0.x, xv0.y, xv0.z, xv0.w, xv1.x, xv1.y, xv1.z, xv1.w};
    const int b0 = (ll >> 3) & 1, b1_ = (ll >> 2) & 1, b2_ = (ll >> 1) & 1, b3 = ll & 1;

    v2f w0v[8], w1v[8];
    #pragma unroll
    for (int i = 0; i < 8; ++i) {
        float sx, cx;
        __sincosf(0.5f * xs[i], &sx, &cx);
        const v2f m00 = Gc[i][0], m01 = Gc[i][1], m10 = Gc[i][2], m11 = Gc[i][3];
        w0v[i].x = fmaf(cx, m00.x,  sx * m01.y);
        w0v[i].y = fmaf(cx, m00.y, -(sx * m01.x));
        w1v[i].x = fmaf(cx, m10.x,  sx * m11.y);
        w1v[i].y = fmaf(cx, m10.y, -(sx * m11.x));
    }

    v2f L = b0 ? w1v[0] : w0v[0];
    {
        const v2f f = b1_ ? w1v[1] : w0v[1];
        v2f t; t.x = fmaf(L.x, f.x, -(L.y * f.y)); t.y = fmaf(L.x, f.y, L.y * f.x); L = t;
    }
    {
        const v2f f = b2_ ? w1v[2] : w0v[2];
        v2f t; t.x = fmaf(L.x, f.x, -(L.y * f.y)); t.y = fmaf(L.x, f.y, L.y * f.x); L = t;
    }
    {
        const v2f f = b3 ? w1v[3] : w0v[3];
        v2f t; t.x = fmaf(L.x, f.x, -(L.y * f.y)); t.y = fmaf(L.x, f.y, L.y * f.x); L = t;
    }

    v2f p45[4], p67[4];
    #pragma unroll
    for (int a = 0; a < 4; ++a) {
        const int bh = (a >> 1) & 1, bl = a & 1;
        const v2f u = bh ? w1v[4] : w0v[4], v = bl ? w1v[5] : w0v[5];
        p45[a].x = fmaf(u.x, v.x, -(u.y * v.y)); p45[a].y = fmaf(u.x, v.y, u.y * v.x);
        const v2f u2 = bh ? w1v[6] : w0v[6], v2_ = bl ? w1v[7] : w0v[7];
        p67[a].x = fmaf(u2.x, v2_.x, -(u2.y * v2_.y)); p67[a].y = fmaf(u2.x, v2_.y, u2.y * v2_.x);
    }
    v2f L45[4];
    #pragma unroll
    for (int a = 0; a < 4; ++a) {
        L45[a].x = fmaf(L.x, p45[a].x, -(L.y * p45[a].y));
        L45[a].y = fmaf(L.x, p45[a].y,   L.y * p45[a].x);
    }
    #pragma unroll
    for (int r = 0; r < 16; ++r) {
        const int a = r >> 2, b = r & 3;
        re[r] = fmaf(L45[a].x, p67[b].x, -(L45[a].y * p67[b].y));
        im[r] = fmaf(L45[a].x, p67[b].y,   L45[a].y * p67[b].x);
    }
}

// ---- signed lane sum: returns sum_l (-1)^{parity(l&DL)} x_l at all lanes ----
template<int DL>
__device__ __forceinline__ float lane_wht(float v, int ll)
{
    if constexpr ((DL & 1) == 0) v += lxorf<1>(v); else v -= lxorf<1>(v);
    if constexpr ((DL & 2) == 0) v += lxorf<2>(v); else v -= lxorf<2>(v);
    if constexpr ((DL & 4) == 0) v += lxorf<4>(v); else v -= lxorf<4>(v);
    if constexpr ((DL & 8) == 0) v += lxorf<8>(v); else v -= lxorf<8>(v);
    if constexpr (DL != 0) {
        int t = ll & DL; t ^= t >> 2; t ^= t >> 1;
        v = (t & 1) ? -v : v;
    }
    return v;
}

// dot of angle-halves with sign pattern from bits of t (qubit i <-> bit 7-i)
__device__ __forceinline__ float dotang(const float* __restrict__ w, int t)
{
    float a = 0.f;
    #pragma unroll
    for (int i = 0; i < 8; ++i) {
        const float h = 0.5f * w[i * 3];
        a += ((t >> (7 - i)) & 1) ? h : -h;
    }
    return a;
}
__device__ __forceinline__ int applyP(M8 m, int u)
{
    int t = 0;
    #pragma unroll
    for (int b = 0; b < 8; ++b)
        t |= (__builtin_popcount((int)m.r[b] & u) & 1) << b;
    return t;
}

__global__ void __launch_bounds__(256)
qae_fused(const float* __restrict__ x, const float* __restrict__ qw,
          const float* __restrict__ w1, const float* __restrict__ b1,
          const float* __restrict__ w2, const float* __restrict__ b2,
          float* __restrict__ out, int nsamp)
{
    __shared__ __align__(16) float dA[16 * 36];
    __shared__ __align__(16) float dB[16 * 36];
    __shared__ __align__(16) float dC[16 * 36];
    __shared__ __align__(16) v2f Gc[8][4];    // layer-0 Rot matrices (init)
    __shared__ v2f RyCS[24];                  // (cos(th/2), sin(th/2)) layers 1..3

    const int tid = threadIdx.x;
    const int u = tid;

    // --- preamble: diag tables in the STORAGE basis via constexpr maps ---
    {
        const int t1 = applyP(P1c, u);
        const int t2 = applyP(P2c, u);
        const int t3 = applyP(P3c, u);
        const float aA = dotang(qw + 24 + 0, t1);                              // phi1
        const float aB = dotang(qw + 24 + 2, t1) + dotang(qw + 48 + 0, t2);    // om1+phi2
        const float aC = dotang(qw + 48 + 2, t2) + dotang(qw + 72 + 0, t3);    // om2+phi3
        const int row = u >> 4, col = u & 15;
        const int idx = row * 36 + col * 2;
        float s_, c_;
        sincosf(aA, &s_, &c_); dA[idx] = c_; dA[idx + 1] = s_;
        sincosf(aB, &s_, &c_); dB[idx] = c_; dB[idx + 1] = s_;
        sincosf(aC, &s_, &c_); dC[idx] = c_; dC[idx + 1] = s_;
    }
    if (tid < 24) {                      // Ry constants, layers 1..3
        const int l = 1 + (tid >> 3), i = tid & 7;
        float s_, c_;
        sincosf(0.5f * qw[l * 24 + i * 3 + 1], &s_, &c_);
        v2f t; t.x = c_; t.y = s_;
        RyCS[tid] = t;
    }
    if (tid >= 32 && tid < 40) {         // layer-0 Rot matrices for init
        const int i = tid - 32;
        const float phi = qw[i * 3 + 0], th = qw[i * 3 + 1], om = qw[i * 3 + 2];
        float s, c, sp, cp, sm, cm;
        sincosf(0.5f * th,         &s,  &c);
        sincosf(0.5f * (phi + om), &sp, &cp);
        sincosf(0.5f * (phi - om), &sm, &cm);
        v2f t;
        t.x =  cp * c; t.y = -sp * c; Gc[i][0] = t;   // m00
        t.x = -cm * s; t.y = -sm * s; Gc[i][1] = t;   // m01
        t.x =  cm * s; t.y = -sm * s; Gc[i][2] = t;   // m10
        t.x =  cp * c; t.y =  sp * c; Gc[i][3] = t;   // m11
    }
    __syncthreads();

    const int sample = (blockIdx.x * 256 + tid) >> 4;
    if (sample >= nsamp) return;
    const int ll = tid & 15;

    float re[16], im[16];
    init_state(x + (size_t)sample * 8, Gc, ll, re, im);

    // layer 1..3: diag then generalized-Ry (rings live only in the constexpr maps)
    diag_apply(re, im, dA, ll);
    gry_layer<1>(re, im, ll, RyCS);
    diag_apply(re, im, dB, ll);
    gry_layer<2>(re, im, ll, RyCS + 8);
    diag_apply(re, im, dC, ll);
    gry_layer<3>(re, im, ll, RyCS + 16);
    // omega3 dropped (|.|^2 readout); ring4 folded into P4 readout duals

    // --- readout: slot FWHT + signed lane butterflies with duals = rows of P4 ---
    float W[16];
    #pragma unroll
    for (int r = 0; r < 16; ++r) W[r] = fmaf(re[r], re[r], im[r] * im[r]);
    #pragma unroll
    for (int b = 0; b < 4; ++b) {
        const int m = 1 << b;
        #pragma unroll
        for (int r = 0; r < 16; ++r) {
            if (!(r & m)) {
                const float a = W[r], bb = W[r ^ m];
                W[r] = a + bb; W[r ^ m] = a - bb;
            }
        }
    }
    float z[8];
    z[0] = lane_wht<(P4c.r[7] >> 4)>(W[P4c.r[7] & 15], ll);
    z[1] = lane_wht<(P4c.r[6] >> 4)>(W[P4c.r[6] & 15], ll);
    z[2] = lane_wht<(P4c.r[5] >> 4)>(W[P4c.r[5] & 15], ll);
    z[3] = lane_wht<(P4c.r[4] >> 4)>(W[P4c.r[4] & 15], ll);
    z[4] = lane_wht<(P4c.r[3] >> 4)>(W[P4c.r[3] & 15], ll);
    z[5] = lane_wht<(P4c.r[2] >> 4)>(W[P4c.r[2] & 15], ll);
    z[6] = lane_wht<(P4c.r[1] >> 4)>(W[P4c.r[1] & 15], ll);
    z[7] = lane_wht<(P4c.r[0] >> 4)>(W[P4c.r[0] & 15], ll);

    // --- MLP: out = w2 · relu(w1 · z + b1) + b2 ---
    if (ll < 8) {
        float h0 = b1[0], h1 = b1[1], h2 = b1[2], h3 = b1[3];
        #pragma unroll
        for (int i = 0; i < 8; ++i) {
            h0 += z[i] * w1[i];
            h1 += z[i] * w1[8 + i];
            h2 += z[i] * w1[16 + i];
            h3 += z[i] * w1[24 + i];
        }
        h0 = fmaxf(h0, 0.f); h1 = fmaxf(h1, 0.f);
        h2 = fmaxf(h2, 0.f); h3 = fmaxf(h3, 0.f);
        const float o = b2[ll] + h0 * w2[ll * 4 + 0] + h1 * w2[ll * 4 + 1]
                                + h2 * w2[ll * 4 + 2] + h3 * w2[ll * 4 + 3];
        out[(size_t)sample * 8 + ll] = o;
    }
}

extern "C" void kernel_launch(void* const* d_in, const int* in_sizes, int n_in,
                              void* d_out, int out_size, void* d_ws, size_t ws_size,
                              hipStream_t stream)
{
    const float* x  = (const float*)d_in[0];
    const float* qw = (const float*)d_in[1];
    const float* w1 = (const float*)d_in[2];
    const float* b1 = (const float*)d_in[3];
    const float* w2 = (const float*)d_in[4];
    const float* b2 = (const float*)d_in[5];
    float* out = (float*)d_out;

    const int nsamp = in_sizes[0] / 8;              // 65536
    const int total_threads = nsamp * 16;           // 16 lanes per sample
    const int blocks = (total_threads + 255) / 256; // 4096

    hipLaunchKernelGGL(qae_fused, dim3(blocks), dim3(256), 0, stream,
                       x, qw, w1, b1, w2, b2, out, nsamp);
}